// Round 11
// baseline (1019.783 us; speedup 1.0000x reference)
//
#include <hip/hip_runtime.h>

#define HID  256
#define DDYN 5
#define NS   27
#define TS   365
#define BS   4            // batch rows per block
#define NW   16           // waves per block
#define UPW  16           // hidden units owned per wave
#define NTILE 3           // 16-col MFMA tiles per wave (one per gate)
#define SA   264          // Abuf row stride in bf16 elems (256 h + 8 pad)
#define G3   768          // 3 gates * 256

typedef short short8 __attribute__((ext_vector_type(8)));
typedef float f32x4  __attribute__((ext_vector_type(4)));

__device__ __forceinline__ unsigned short f2bf(float f) {
    union { float f; unsigned u; } v; v.f = f;
    unsigned r = v.u + 0x7FFFu + ((v.u >> 16) & 1u);   // RNE
    return (unsigned short)(r >> 16);
}
__device__ __forceinline__ float bf2f(unsigned short s) {
    union { unsigned u; float f; } v; v.u = ((unsigned)s) << 16;
    return v.f;
}
__device__ __forceinline__ float bf2f_s(short s) {
    union { unsigned u; float f; } v; v.u = ((unsigned)(unsigned short)s) << 16;
    return v.f;
}
__device__ __forceinline__ float fsig(float x) {
    float e = __builtin_amdgcn_exp2f(-1.4426950408889634f * x);
    return __builtin_amdgcn_rcpf(1.0f + e);
}
__device__ __forceinline__ float ftanh(float x) {
    float e = __builtin_amdgcn_exp2f(2.8853900817779268f * x);
    return 1.0f - 2.0f * __builtin_amdgcn_rcpf(1.0f + e);
}

// Validated register plan (R8/R10): Bf 96 regs pinned to AGPR after build
// (spill traffic 270 MB -> 0), acc unpinned in arch VGPRs (per-step acc pin
// cost 620 us of accvgpr/hazard stalls in R8). R10 post-mortem: memory clean
// but phase A stall-bound. This round: (1) BROADCAST A-rows — lanes n>=4
// read the same LDS addresses as rows n&3 (rows 4..15 of A are zero padding;
// reading them wasted 75% of phase-A LDS bandwidth; same-address reads
// broadcast conflict-free; MFMA's garbage rows 4..15 are never stored);
// (2) batch ds_reads in PAIRS (clobber every 2 chunks): 2 frags in flight
// halves exposed LDS latency, costs only +4 arch regs.
__global__ __launch_bounds__(1024)
void ealstm_kernel(const float* __restrict__ x_dyn,  const float* __restrict__ x_stat,
                   const float* __restrict__ W_i,    const float* __restrict__ b_i,
                   const float* __restrict__ W_f,    const float* __restrict__ b_f,
                   const float* __restrict__ W_g,    const float* __restrict__ b_g,
                   const float* __restrict__ W_o,    const float* __restrict__ b_o,
                   const float* __restrict__ W_head, const float* __restrict__ b_head,
                   float* __restrict__ out)
{
    // LDS: 16896 + 12288 + 12288 + 23360 + 432 = 65264 B (<= 64 KiB)
    __shared__ __align__(16) unsigned short Abuf[2][16 * SA]; // h-only A tile, double-buffered
    __shared__ __align__(16) float          pre[NW * 192];    // h-part preacts, wave-private
    __shared__ __align__(16) unsigned short WxL[G3 * 8];      // per col: Wx[0..4], bias, 0, 0 (bf16)
    __shared__ __align__(16) unsigned short xcA[TS * 4 * 8];  // per (t,row): x[0..4], 1.0, 0, 0 (bf16)
    __shared__ __align__(16) float          xst[BS * NS];

    const int tid  = threadIdx.x;
    const int bid  = blockIdx.x;
    const int b0   = bid * BS;
    const int lane = tid & 63;
    const int wv   = tid >> 6;        // wave 0..15
    const int q    = lane >> 4;       // quad 0..3 (MFMA K-group)
    const int n    = lane & 15;       // MFMA col-in-tile
    const int up   = lane >> 2;       // unit-local 0..15 (phase B)
    const int r    = lane & 3;        // batch row 0..3 (phase B)
    const int u    = wv * UPW + up;   // owned hidden unit (phase B)

    // ---- init LDS ----
    for (int i = tid; i < 2 * 16 * SA / 2; i += 1024)
        ((unsigned int*)Abuf)[i] = 0u;                 // zero both A buffers (h0 = 0)
    for (int i = tid; i < BS * NS; i += 1024)
        xst[i] = x_stat[(b0 + i / NS) * NS + (i % NS)];
    for (int i = tid; i < TS * BS; i += 1024) {        // x rows, 16B-aligned per (t,row)
        int t = i >> 2, rr = i & 3;
        const float* xp = x_dyn + ((size_t)(b0 + rr) * TS + t) * DDYN;
        unsigned short* dst = &xcA[(unsigned)i * 8];
        #pragma unroll
        for (int d = 0; d < DDYN; d++) dst[d] = f2bf(xp[d]);
        dst[5] = 0x3F80; dst[6] = 0; dst[7] = 0;
    }
    if (tid < G3) {
        int col = tid;
        int gate = col >> 8, hc = col & 255;
        const float* Wg = gate == 0 ? W_f : (gate == 1 ? W_g : W_o);
        const float* bg = gate == 0 ? b_f : (gate == 1 ? b_g : b_o);
        #pragma unroll
        for (int d = 0; d < DDYN; d++) WxL[col * 8 + d] = f2bf(Wg[hc * (DDYN + HID) + d]);
        WxL[col * 8 + 5] = f2bf(bg[hc]);
        WxL[col * 8 + 6] = 0; WxL[col * 8 + 7] = 0;
    }

    // ---- persistent B fragments: 3 tiles x 8 K-chunks x 4 regs = 96, pinned to AGPR ----
    short8 Bf[NTILE][8];
    #pragma unroll
    for (int j = 0; j < NTILE; j++) {
        int urow = wv * UPW + n;           // weight row (hidden unit), gate j
        const float* Wg = j == 0 ? W_f : (j == 1 ? W_g : W_o);
        const float* wrow = Wg + urow * (DDYN + HID) + DDYN;   // skip x-part
        #pragma unroll
        for (int c = 0; c < 8; c++) {
            int k0 = c * 32 + q * 8;
            short8 fr;
            #pragma unroll
            for (int e = 0; e < 8; e++) fr[e] = (short)f2bf(wrow[k0 + e]);
            Bf[j][c] = fr;
        }
    }
    // Pin weight fragments into AGPR (one-time v_accvgpr_writes; MFMA reads
    // them in place). Pin-after-build: construction-time pin NaN'd (R9).
    #pragma unroll
    for (int j = 0; j < NTILE; j++)
        #pragma unroll
        for (int c = 0; c < 8; c++)
            __asm__("" : "+a"(Bf[j][c]));
    __syncthreads();

    // ---- i_gate for this thread's (unit u, row r) ----
    float ig, cst = 0.f;
    {
        float a = b_i[u];
        for (int s = 0; s < NS; s++)
            a += xst[r * NS + s] * W_i[u * NS + s];
        ig = fsig(a);
    }
    __syncthreads();

    // BROADCAST: rows 4..15 of A are zero pad; read row n&3 instead. MFMA's
    // rows 4..15 become duplicates, which are never stored (q==0 store only).
    const int aoff  = (n & 3) * SA;
    const int pbase = wv * 192 + lane;    // phase-B read base (gate 0)

    // ---- time loop: ONE barrier per step ----
    for (int t = 0; t < TS; t++) {
        const unsigned short* __restrict__ pA = Abuf[t & 1];
        unsigned short*       __restrict__ pB = Abuf[(t + 1) & 1];

        // Phase A: h-part preacts (8 K-chunks, fully unrolled -> Bf static).
        f32x4 acc[NTILE];
        #pragma unroll
        for (int j = 0; j < NTILE; j++) acc[j] = (f32x4){0.f, 0.f, 0.f, 0.f};
        #pragma unroll
        for (int c = 0; c < 8; c++) {
            short8 a = *(const short8*)&pA[aoff + c * 32 + q * 8];
            #pragma unroll
            for (int j = 0; j < NTILE; j++)
                acc[j] = __builtin_amdgcn_mfma_f32_16x16x32_bf16(a, Bf[j][c], acc[j], 0, 0, 0);
            // clobber every 2 chunks: <=2 A-frags in flight (batch ds_reads
            // in pairs; per-chunk clobber fully serialized read->MFMA->read)
            if (c & 1) __asm__ volatile("" ::: "memory");
        }
        if (q == 0) {   // lanes 0..15 hold rows 0..3 of col n -> wave-private pre region
            #pragma unroll
            for (int j = 0; j < NTILE; j++)
                *(f32x4*)&pre[wv * 192 + j * 64 + n * 4] = acc[j];
        }
        // intra-wave exchange: wave's own writes -> wave's own reads
        __asm__ volatile("s_waitcnt lgkmcnt(0)" ::: "memory");

        // Phase B: LSTM cell for (unit u, row r); x·Wx + bias folded in here
        {
            short8 xv = *(const short8*)&xcA[(unsigned)(t * 4 + r) * 8];
            short8 wf = *(const short8*)&WxL[(u)        * 8];
            short8 wg = *(const short8*)&WxL[(256 + u)  * 8];
            short8 wo = *(const short8*)&WxL[(512 + u)  * 8];
            float pf = pre[pbase]       + bf2f_s(wf[5]);
            float pg = pre[pbase + 64]  + bf2f_s(wg[5]);
            float po = pre[pbase + 128] + bf2f_s(wo[5]);
            #pragma unroll
            for (int d = 0; d < DDYN; d++) {
                float xd = bf2f_s(xv[d]);
                pf += xd * bf2f_s(wf[d]);
                pg += xd * bf2f_s(wg[d]);
                po += xd * bf2f_s(wo[d]);
            }
            float f  = fsig(pf);
            float g_ = ftanh(pg);
            float o  = fsig(po);
            cst = f * cst + ig * g_;
            float h = o * ftanh(cst);
            pB[r * SA + u] = f2bf(h);
        }
        __syncthreads();
    }

    // ---- head: out[b] = h . W_head + b_head (TS odd -> final h in buffer 1) ----
    {
        float h = bf2f(Abuf[1][r * SA + u]);
        pre[u * 4 + r] = h * W_head[u];
    }
    __syncthreads();
    if (tid < 64) {
        f32x4 s = *(const f32x4*)&pre[tid * 4];
        #pragma unroll
        for (int k = 1; k < 4; k++) {
            f32x4 v = *(const f32x4*)&pre[(tid + k * 64) * 4];
            #pragma unroll
            for (int rr = 0; rr < BS; rr++) s[rr] += v[rr];
        }
        #pragma unroll
        for (int off = 32; off > 0; off >>= 1)
            #pragma unroll
            for (int rr = 0; rr < BS; rr++) s[rr] += __shfl_down(s[rr], off, 64);
        if (tid == 0) {
            float bh = b_head[0];
            #pragma unroll
            for (int rr = 0; rr < BS; rr++) out[b0 + rr] = s[rr] + bh;
        }
    }
}

extern "C" void kernel_launch(void* const* d_in, const int* in_sizes, int n_in,
                              void* d_out, int out_size, void* d_ws, size_t ws_size,
                              hipStream_t stream) {
    ealstm_kernel<<<256, 1024, 0, stream>>>(
        (const float*)d_in[0],  (const float*)d_in[1],  (const float*)d_in[2],
        (const float*)d_in[3],  (const float*)d_in[4],  (const float*)d_in[5],
        (const float*)d_in[6],  (const float*)d_in[7],  (const float*)d_in[8],
        (const float*)d_in[9],  (const float*)d_in[10], (const float*)d_in[11],
        (float*)d_out);
}

// Round 12
// 785.363 us; speedup vs baseline: 1.2985x; 1.2985x over previous
//
#include <hip/hip_runtime.h>

#define HID  256
#define DDYN 5
#define NS   27
#define TS   365
#define BS   4            // batch rows per block
#define NW   8            // waves per block
#define UPW  32           // hidden units owned per wave
#define NTILE 6           // 16-col MFMA tiles per wave (32 units x 3 gates / 16)
#define SA   264          // Abuf row stride in bf16 elems (256 h + 8 pad)
#define G3   768          // 3 gates * 256

typedef short short8 __attribute__((ext_vector_type(8)));
typedef float f32x4  __attribute__((ext_vector_type(4)));

__device__ __forceinline__ unsigned short f2bf(float f) {
    union { float f; unsigned u; } v; v.f = f;
    unsigned r = v.u + 0x7FFFu + ((v.u >> 16) & 1u);   // RNE
    return (unsigned short)(r >> 16);
}
__device__ __forceinline__ float bf2f(unsigned short s) {
    union { unsigned u; float f; } v; v.u = ((unsigned)s) << 16;
    return v.f;
}
__device__ __forceinline__ float bf2f_s(short s) {
    union { unsigned u; float f; } v; v.u = ((unsigned)(unsigned short)s) << 16;
    return v.f;
}
__device__ __forceinline__ float fsig(float x) {
    float e = __builtin_amdgcn_exp2f(-1.4426950408889634f * x);
    return __builtin_amdgcn_rcpf(1.0f + e);
}
__device__ __forceinline__ float ftanh(float x) {
    float e = __builtin_amdgcn_exp2f(2.8853900817779268f * x);
    return 1.0f - 2.0f * __builtin_amdgcn_rcpf(1.0f + e);
}

// R11 post-mortem: the limiter is LDS BANDWIDTH, not registers/spills.
// Phase A moves 1 KB per ds_read_b128 regardless of row duplication; at
// 16 waves that's 128 KB/step/CU (~1500 cyc). This kernel halves it:
// 8 waves x 6 tiles (512 thr). Register plan: Bf = 192 regs PINNED to AGPR
// (pin-after-build — R8/R10-validated resident, R9's construction-time pin
// NaN'd); arch ~64 (acc 24 + frags + temps); 256/wave = 2 waves/SIMD budget
// granted by launch_bounds(512,2) + waves_per_eu(2,2). The pin forces the
// allocator to the 2-wave budget that attributes alone never achieved (R2).
__global__ __launch_bounds__(512, 2)
__attribute__((amdgpu_waves_per_eu(2, 2)))
void ealstm_kernel(const float* __restrict__ x_dyn,  const float* __restrict__ x_stat,
                   const float* __restrict__ W_i,    const float* __restrict__ b_i,
                   const float* __restrict__ W_f,    const float* __restrict__ b_f,
                   const float* __restrict__ W_g,    const float* __restrict__ b_g,
                   const float* __restrict__ W_o,    const float* __restrict__ b_o,
                   const float* __restrict__ W_head, const float* __restrict__ b_head,
                   float* __restrict__ out)
{
    // LDS: 16896 + 12288 + 12288 + 23360 + 432 = 65264 B (<= 64 KiB)
    __shared__ __align__(16) unsigned short Abuf[2][16 * SA]; // h-only A tile, double-buffered
    __shared__ __align__(16) float          pre[NW * 384];    // preacts, wave-private regions
    __shared__ __align__(16) unsigned short WxL[G3 * 8];      // per col: Wx[0..4], bias, 0, 0 (bf16)
    __shared__ __align__(16) unsigned short xcA[TS * 4 * 8];  // per (t,row): x[0..4], 1.0, 0, 0 (bf16)
    __shared__ __align__(16) float          xst[BS * NS];

    const int tid  = threadIdx.x;
    const int bid  = blockIdx.x;
    const int b0   = bid * BS;
    const int lane = tid & 63;
    const int wv   = tid >> 6;        // wave 0..7
    const int q    = lane >> 4;       // quad 0..3 (MFMA K-group)
    const int n    = lane & 15;       // MFMA col-in-tile
    const int ul   = lane >> 2;       // unit-local 0..15 (phase B)
    const int r    = lane & 3;        // batch row 0..3 (phase B)
    const int ua   = wv * UPW + ul;       // owned hidden unit A (phase B)
    const int ub   = ua + 16;             // owned hidden unit B (phase B)

    // ---- init LDS ----
    for (int i = tid; i < 2 * 16 * SA / 2; i += 512)
        ((unsigned int*)Abuf)[i] = 0u;                 // zero both A buffers (h0 = 0)
    for (int i = tid; i < BS * NS; i += 512)
        xst[i] = x_stat[(b0 + i / NS) * NS + (i % NS)];
    for (int i = tid; i < TS * BS; i += 512) {         // x rows, 16B-aligned per (t,row)
        int t = i >> 2, rr = i & 3;
        const float* xp = x_dyn + ((size_t)(b0 + rr) * TS + t) * DDYN;
        unsigned short* dst = &xcA[(unsigned)i * 8];
        #pragma unroll
        for (int d = 0; d < DDYN; d++) dst[d] = f2bf(xp[d]);
        dst[5] = 0x3F80; dst[6] = 0; dst[7] = 0;
    }
    for (int col = tid; col < G3; col += 512) {
        int gate = col >> 8, hc = col & 255;
        const float* Wg = gate == 0 ? W_f : (gate == 1 ? W_g : W_o);
        const float* bg = gate == 0 ? b_f : (gate == 1 ? b_g : b_o);
        #pragma unroll
        for (int d = 0; d < DDYN; d++) WxL[col * 8 + d] = f2bf(Wg[hc * (DDYN + HID) + d]);
        WxL[col * 8 + 5] = f2bf(bg[hc]);
        WxL[col * 8 + 6] = 0; WxL[col * 8 + 7] = 0;
    }

    // ---- persistent B fragments: 6 tiles x 8 K-chunks x 4 regs = 192 ----
    // tile j: gate = j>>1, unit-local base = (j&1)*16
    short8 Bf[NTILE][8];
    #pragma unroll
    for (int j = 0; j < NTILE; j++) {
        int urow = wv * UPW + (j & 1) * 16 + n;   // weight row (hidden unit)
        int g = j >> 1;
        const float* Wg = g == 0 ? W_f : (g == 1 ? W_g : W_o);
        const float* wrow = Wg + urow * (DDYN + HID) + DDYN;   // skip x-part
        #pragma unroll
        for (int c = 0; c < 8; c++) {
            int k0 = c * 32 + q * 8;
            short8 fr;
            #pragma unroll
            for (int e = 0; e < 8; e++) fr[e] = (short)f2bf(wrow[k0 + e]);
            Bf[j][c] = fr;
        }
    }
    // Pin weight fragments into AGPR (one-time v_accvgpr_writes; MFMA reads
    // them in place). Pin-after-build: construction-time pin NaN'd (R9).
    #pragma unroll
    for (int j = 0; j < NTILE; j++)
        #pragma unroll
        for (int c = 0; c < 8; c++)
            __asm__("" : "+a"(Bf[j][c]));
    __syncthreads();

    // ---- i_gate for (ua, r) and (ub, r) ----
    float iga, igb, ca = 0.f, cb = 0.f;
    {
        float a0 = b_i[ua], a1 = b_i[ub];
        for (int s = 0; s < NS; s++) {
            float xs = xst[r * NS + s];
            a0 += xs * W_i[ua * NS + s];
            a1 += xs * W_i[ub * NS + s];
        }
        iga = fsig(a0); igb = fsig(a1);
    }
    __syncthreads();

    const int aoff  = n * SA;
    const int pbase = wv * 384 + ul * 4 + r;   // phase-B base (gate 0, unit-low)

    // ---- time loop: ONE barrier per step ----
    for (int t = 0; t < TS; t++) {
        const unsigned short* __restrict__ pA = Abuf[t & 1];
        unsigned short*       __restrict__ pB = Abuf[(t + 1) & 1];

        // Phase A: h-part preacts (8 K-chunks, fully unrolled -> Bf static).
        f32x4 acc[NTILE];
        #pragma unroll
        for (int j = 0; j < NTILE; j++) acc[j] = (f32x4){0.f, 0.f, 0.f, 0.f};
        #pragma unroll
        for (int c = 0; c < 8; c++) {
            short8 a = *(const short8*)&pA[aoff + c * 32 + q * 8];
            #pragma unroll
            for (int j = 0; j < NTILE; j++)
                acc[j] = __builtin_amdgcn_mfma_f32_16x16x32_bf16(a, Bf[j][c], acc[j], 0, 0, 0);
            // per-chunk clobber (R7-validated): <=2 A-frags in flight
            __asm__ volatile("" ::: "memory");
        }
        if (q == 0) {   // lanes 0..15 hold rows 0..3 of col n -> wave-private pre
            #pragma unroll
            for (int j = 0; j < NTILE; j++)
                *(f32x4*)&pre[wv * 384 + j * 64 + n * 4] = acc[j];
        }
        // intra-wave exchange: wave's own writes -> wave's own reads
        __asm__ volatile("s_waitcnt lgkmcnt(0)" ::: "memory");

        // Phase B: LSTM cell for (ua, r) then (ub, r); x·Wx + bias folded in
        {
            short8 xv = *(const short8*)&xcA[(unsigned)(t * 4 + r) * 8];
            float xd[DDYN];
            #pragma unroll
            for (int d = 0; d < DDYN; d++) xd[d] = bf2f_s(xv[d]);

            {   // unit-low: tiles j = 0, 2, 4
                short8 wf = *(const short8*)&WxL[(ua)        * 8];
                short8 wg = *(const short8*)&WxL[(256 + ua)  * 8];
                short8 wo = *(const short8*)&WxL[(512 + ua)  * 8];
                float pf = pre[pbase]       + bf2f_s(wf[5]);
                float pg = pre[pbase + 128] + bf2f_s(wg[5]);
                float po = pre[pbase + 256] + bf2f_s(wo[5]);
                #pragma unroll
                for (int d = 0; d < DDYN; d++) {
                    pf += xd[d] * bf2f_s(wf[d]);
                    pg += xd[d] * bf2f_s(wg[d]);
                    po += xd[d] * bf2f_s(wo[d]);
                }
                float f  = fsig(pf);
                float g_ = ftanh(pg);
                float o  = fsig(po);
                ca = f * ca + iga * g_;
                float h = o * ftanh(ca);
                pB[r * SA + ua] = f2bf(h);
            }
            {   // unit-high: tiles j = 1, 3, 5
                short8 wf = *(const short8*)&WxL[(ub)        * 8];
                short8 wg = *(const short8*)&WxL[(256 + ub)  * 8];
                short8 wo = *(const short8*)&WxL[(512 + ub)  * 8];
                float pf = pre[pbase + 64]  + bf2f_s(wf[5]);
                float pg = pre[pbase + 192] + bf2f_s(wg[5]);
                float po = pre[pbase + 320] + bf2f_s(wo[5]);
                #pragma unroll
                for (int d = 0; d < DDYN; d++) {
                    pf += xd[d] * bf2f_s(wf[d]);
                    pg += xd[d] * bf2f_s(wg[d]);
                    po += xd[d] * bf2f_s(wo[d]);
                }
                float f  = fsig(pf);
                float g_ = ftanh(pg);
                float o  = fsig(po);
                cb = f * cb + igb * g_;
                float h = o * ftanh(cb);
                pB[r * SA + ub] = f2bf(h);
            }
        }
        __syncthreads();
    }

    // ---- head: out[b] = h . W_head + b_head (TS odd -> final h in buffer 1) ----
    {
        float ha = bf2f(Abuf[1][r * SA + ua]);
        float hb = bf2f(Abuf[1][r * SA + ub]);
        pre[ua * 4 + r] = ha * W_head[ua];
        pre[ub * 4 + r] = hb * W_head[ub];
    }
    __syncthreads();
    if (tid < 64) {
        f32x4 s = *(const f32x4*)&pre[tid * 4];
        #pragma unroll
        for (int k = 1; k < 4; k++) {
            f32x4 v = *(const f32x4*)&pre[(tid + k * 64) * 4];
            #pragma unroll
            for (int rr = 0; rr < BS; rr++) s[rr] += v[rr];
        }
        #pragma unroll
        for (int off = 32; off > 0; off >>= 1)
            #pragma unroll
            for (int rr = 0; rr < BS; rr++) s[rr] += __shfl_down(s[rr], off, 64);
        if (tid == 0) {
            float bh = b_head[0];
            #pragma unroll
            for (int rr = 0; rr < BS; rr++) out[b0 + rr] = s[rr] + bh;
        }
    }
}

extern "C" void kernel_launch(void* const* d_in, const int* in_sizes, int n_in,
                              void* d_out, int out_size, void* d_ws, size_t ws_size,
                              hipStream_t stream) {
    ealstm_kernel<<<256, 512, 0, stream>>>(
        (const float*)d_in[0],  (const float*)d_in[1],  (const float*)d_in[2],
        (const float*)d_in[3],  (const float*)d_in[4],  (const float*)d_in[5],
        (const float*)d_in[6],  (const float*)d_in[7],  (const float*)d_in[8],
        (const float*)d_in[9],  (const float*)d_in[10], (const float*)d_in[11],
        (float*)d_out);
}